// Round 7
// baseline (711.397 us; speedup 1.0000x reference)
//
#include <hip/hip_runtime.h>

// ---------------------------------------------------------------------------
// IntegerCifar10Net: 4-bit quantized CNN, B=512.
// Post-layer-1 math is EXACT integer arithmetic (acts 0..7, weights -7..7)
// on i8 MFMA (mfma_i32_16x16x64_i8) -- round-4 conv structure (best measured).
// Layer 1: pure fp32 main path + rigorous boundary screening; flagged outputs
// (quant decision within tau of a rint boundary) are appended to a global
// list and recomputed bit-exactly in fp64 by a tiny fixup kernel (identical
// accumulation order to the proven round-2 kernel).
// Activations NHWC u8 (value = 7 * real). Epilogue fp64 affine+rint.
// ---------------------------------------------------------------------------

typedef __attribute__((ext_vector_type(4))) int v4i;

// workspace offsets (bytes)
#define O_WD1    0u          // 13824   f64 conv1 [64][3][9]
#define O_WS1    13824u      // 6912    f32 conv1 [64][3][9]
#define O_QWF2   20736u      // 5120    i8 fc2 [10][512]
#define O_QWT2   25856u      // 36864   i8 [64][9][64]
#define O_QWT3   62720u      // 73728   i8 [128][9][64]
#define O_QWT4   136448u     // 147456  i8 [128][9][128]
#define O_QWT5   283904u     // 294912  i8 [256][9][128]
#define O_QWT6   578816u     // 589824  i8 [256][9][256]
#define O_QWF1   1168640u    // 2097152 i8 [512][4096] nhwc-k
#define O_BUFA   3265792u    // 33.5 MB
#define O_BUFB   36820224u   // 8.4 MB -> ends 45208832
#define O_CNT    45208832u   // 4 (pad 128)
#define O_LIST   45208960u   // 4 MB (CAP entries)  -> ends ~49.4 MB (<=50.3 proven)
#define FIX_CAP  (1u << 20)

// prep segment boundaries (element index)
#define S_W1   0
#define S_WF2  1728
#define S_W2   6848
#define S_W3   43712
#define S_W4   117440
#define S_W5   264896
#define S_W6   559808
#define S_WF1  1149632
#define S_END  3246784

// ---------------------------------------------------------------------------
// fused weight prep (also zeroes the fixup counter)
// ---------------------------------------------------------------------------
__device__ __forceinline__ int qround(float w) {
    double t = fmin(fmax((double)w, -1.0), 1.0) * 7.0;
    return (int)rint(t);
}

__global__ void prep_k(const float* __restrict__ w1, const float* __restrict__ w2,
                       const float* __restrict__ w3, const float* __restrict__ w4,
                       const float* __restrict__ w5, const float* __restrict__ w6,
                       const float* __restrict__ wf1, const float* __restrict__ wf2,
                       char* __restrict__ ws) {
    int i = blockIdx.x * 256 + threadIdx.x;
    if (i == 0) *(unsigned*)(ws + O_CNT) = 0u;
    if (i >= S_END) return;
    if (i < S_WF2) {
        int r = qround(w1[i]);
        ((double*)(ws + O_WD1))[i] = (double)r;
        ((float*)(ws + O_WS1))[i]  = (float)r;
    } else if (i < S_W2) {
        int j = i - S_WF2;
        ((signed char*)(ws + O_QWF2))[j] = (signed char)qround(wf2[j]);
    } else if (i < S_WF1) {
        const float* src; signed char* dst; int CI, j;
        if      (i < S_W3) { src = w2; dst = (signed char*)(ws + O_QWT2); CI = 64;  j = i - S_W2; }
        else if (i < S_W4) { src = w3; dst = (signed char*)(ws + O_QWT3); CI = 64;  j = i - S_W3; }
        else if (i < S_W5) { src = w4; dst = (signed char*)(ws + O_QWT4); CI = 128; j = i - S_W4; }
        else if (i < S_W6) { src = w5; dst = (signed char*)(ws + O_QWT5); CI = 128; j = i - S_W5; }
        else               { src = w6; dst = (signed char*)(ws + O_QWT6); CI = 256; j = i - S_W6; }
        int co  = j / (9 * CI);
        int rem = j - co * 9 * CI;
        int t   = rem / CI;
        int ci  = rem - t * CI;
        dst[j] = (signed char)qround(src[(co * CI + ci) * 9 + t]);
    } else {
        int j  = i - S_WF1;
        int row = j >> 12;
        int kn  = j & 4095;
        int px  = kn >> 8;
        int c   = kn & 255;
        ((signed char*)(ws + O_QWF1))[j] = (signed char)qround(wf1[row * 4096 + c * 16 + px]);
    }
}

// ---------------------------------------------------------------------------
// conv1: 3->64, 32x32, pure fp32 + boundary screening -> append to fixup list.
// ---------------------------------------------------------------------------
__global__ __launch_bounds__(256) void conv1_k(
    const float* __restrict__ x, const float* __restrict__ wf32,
    const float* __restrict__ gvec, const float* __restrict__ bvec,
    unsigned char* __restrict__ out, unsigned* __restrict__ cnt,
    unsigned* __restrict__ list)
{
    __shared__ float xs[3][10][35];

    const int tid  = threadIdx.x;
    const int sp   = tid & 63;
    const int cg   = __builtin_amdgcn_readfirstlane(tid >> 6);
    const int img  = blockIdx.x >> 2;
    const int slab = blockIdx.x & 3;
    const int y0s  = slab * 8;
    const int co_base = blockIdx.y * 16;
    const int co0  = co_base + cg * 4;        // uniform
    const int yb = sp >> 4, xb = sp & 15;
    const int ysl = yb * 2, x0 = xb * 2;

    for (int i = tid; i < 1020; i += 256) {
        int ci = i / 340, r = i - ci * 340;
        int ry = r / 34, rx = r - ry * 34;
        int gy = y0s - 1 + ry, gx = rx - 1;
        float v = 0.f;
        if ((unsigned)gy < 32u && (unsigned)gx < 32u)
            v = x[(img * 3 + ci) * 1024 + gy * 32 + gx];
        xs[ci][ry][rx] = v;
    }
    __syncthreads();

    float accS[4][4];
    float xa[4];
#pragma unroll
    for (int l = 0; l < 4; ++l)
#pragma unroll
        for (int p = 0; p < 4; ++p) accS[l][p] = 0.f;
#pragma unroll
    for (int p = 0; p < 4; ++p) xa[p] = 0.f;

#pragma unroll
    for (int ci = 0; ci < 3; ++ci) {
        float a[4][4];
#pragma unroll
        for (int iy = 0; iy < 4; ++iy)
#pragma unroll
            for (int ix = 0; ix < 4; ++ix)
                a[iy][ix] = xs[ci][ysl + iy][x0 + ix];
#pragma unroll
        for (int ky = 0; ky < 3; ++ky)
#pragma unroll
            for (int kx = 0; kx < 3; ++kx) {
                xa[0] += fabsf(a[ky    ][kx    ]);
                xa[1] += fabsf(a[ky    ][kx + 1]);
                xa[2] += fabsf(a[ky + 1][kx    ]);
                xa[3] += fabsf(a[ky + 1][kx + 1]);
            }
#pragma unroll
        for (int l = 0; l < 4; ++l) {
            const float* wp = wf32 + ((co0 + l) * 3 + ci) * 9;  // uniform -> s_load
            float wr[9];
#pragma unroll
            for (int t = 0; t < 9; ++t) wr[t] = wp[t];
#pragma unroll
            for (int ky = 0; ky < 3; ++ky)
#pragma unroll
                for (int kx = 0; kx < 3; ++kx) {
                    const float wv = wr[ky * 3 + kx];
                    accS[l][0] = fmaf(wv, a[ky    ][kx    ], accS[l][0]);
                    accS[l][1] = fmaf(wv, a[ky    ][kx + 1], accS[l][1]);
                    accS[l][2] = fmaf(wv, a[ky + 1][kx    ], accS[l][2]);
                    accS[l][3] = fmaf(wv, a[ky + 1][kx + 1], accS[l][3]);
                }
        }
    }

#pragma unroll
    for (int l = 0; l < 4; ++l) {
        const int co = co0 + l;
        const float gg = gvec[co];
        const float bb = bvec[co];
#pragma unroll
        for (int p = 0; p < 4; ++p) {
            float conv = accS[l][p] * (1.f / 7.f);
            float y  = fmaf(conv, gg, bb);
            float t  = fminf(fmaxf(y, -1.f), 1.f) * 7.f;
            // conservative bound (>= 1.7x gamma_27 analysis + absolute slack)
            float tau = fabsf(gg) * xa[p] * 2e-5f + 1e-4f;
            float u = t - floorf(t);
            float d = fabsf(u - 0.5f);
            int q = (int)rintf(t);
            q = q > 0 ? q : 0;
            const int Y = y0s + ysl + (p >> 1), X = x0 + (p & 1);
            const unsigned id = (unsigned)(((img * 32 + Y) * 32 + X) * 64 + co);
            out[id] = (unsigned char)q;
            if (d <= tau) {                     // rare: defer exact recompute
                unsigned idx = atomicAdd(cnt, 1u);
                if (idx < FIX_CAP) list[idx] = id;
            }
        }
    }
}

// ---------------------------------------------------------------------------
// fixup: bit-exact fp64 recompute (identical order to proven round-2 chain)
// for the flagged outputs only.
// ---------------------------------------------------------------------------
__global__ __launch_bounds__(256) void fixup1_k(
    const float* __restrict__ x, const double* __restrict__ wd64,
    const float* __restrict__ gvec, const float* __restrict__ bvec,
    unsigned char* __restrict__ out, const unsigned* __restrict__ cnt,
    const unsigned* __restrict__ list)
{
    const unsigned total = min(*cnt, FIX_CAP);
    for (unsigned i = blockIdx.x * 256 + threadIdx.x; i < total;
         i += gridDim.x * 256) {
        const unsigned id = list[i];
        const int co  = id & 63;
        unsigned r    = id >> 6;
        const int X   = r & 31; r >>= 5;
        const int Y   = r & 31;
        const int img = r >> 5;
        double acc = 0.0;
#pragma unroll
        for (int ci = 0; ci < 3; ++ci)
#pragma unroll
            for (int ky = 0; ky < 3; ++ky)
#pragma unroll
                for (int kx = 0; kx < 3; ++kx) {
                    const int gy = Y - 1 + ky, gx = X - 1 + kx;
                    double v = 0.0;
                    if ((unsigned)gy < 32u && (unsigned)gx < 32u)
                        v = (double)x[(img * 3 + ci) * 1024 + gy * 32 + gx];
                    acc = fma(wd64[(co * 3 + ci) * 9 + ky * 3 + kx], v, acc);
                }
        double conv = acc / 7.0;
        double y = conv * (double)gvec[co] + (double)bvec[co];
        double t = fmin(fmax(y, -1.0), 1.0) * 7.0;
        int q = (int)rint(t);
        q = q > 0 ? q : 0;
        out[id] = (unsigned char)q;
    }
}

// ---------------------------------------------------------------------------
// i8 MFMA implicit-GEMM conv (round-4 structure, best measured).
// ---------------------------------------------------------------------------
template<int CI, int CO, int H, int W, bool POOL, int IPB>
__global__ __launch_bounds__(256, 2) void conv_i8_k(
    const unsigned char* __restrict__ in, const signed char* __restrict__ wt,
    const float* __restrict__ gvec, const float* __restrict__ bvec,
    unsigned char* __restrict__ out)
{
    constexpr int ATX    = (IPB == 1) ? 18 : 10;
    constexpr int APX    = ATX * ATX;
    constexpr int APLANE = IPB * APX * 16;
    constexpr int WBASE  = 4 * APLANE;
    constexpr int WPLANE = 576 * 16;
    constexpr int NPASS  = CI / 64;

    __shared__ __align__(16) char lds[WBASE + 4 * WPLANE];

    const int tid = threadIdx.x;
    const int l   = tid & 63;
    const int w   = tid >> 6;
    const int n   = l & 15;
    const int q   = l >> 4;

    int img = 0, regY0 = 0, regX0 = 0, wy8 = 0, wx8 = 0, tilepx = 0;
    if (IPB == 1) {
        constexpr int rpw = W / 16;
        constexpr int rpi = (H / 16) * rpw;
        img   = blockIdx.x / rpi;
        int r = blockIdx.x % rpi;
        regY0 = (r / rpw) * 16;
        regX0 = (r % rpw) * 16;
        wy8 = (w >> 1) * 8; wx8 = (w & 1) * 8;
    } else {
        tilepx = w * APX;
    }
    const int co_base = blockIdx.y * 64;

    const int ly = ((n >> 3) & 1) * 2 + ((n >> 1) & 1);
    const int lx = ((n >> 2) & 1) * 2 + (n & 1);

    int abase[4], wbase[4];
#pragma unroll
    for (int ps = 0; ps < 4; ++ps) {
        int ay0 = wy8 + (ps >> 1) * 4 + ly;
        int ax0 = wx8 + (ps & 1) * 4 + lx;
        abase[ps] = q * APLANE + (tilepx + ay0 * ATX + ax0) * 16;
    }
#pragma unroll
    for (int cs = 0; cs < 4; ++cs)
        wbase[cs] = WBASE + q * WPLANE + ((cs * 16 + n) * 9) * 16;

    v4i acc[4][4];
#pragma unroll
    for (int ps = 0; ps < 4; ++ps)
#pragma unroll
        for (int cs = 0; cs < 4; ++cs)
            acc[ps][cs] = (v4i)0;

    for (int pass = 0; pass < NPASS; ++pass) {
        const int cib = pass * 64;
        __syncthreads();
        for (int i = tid; i < IPB * APX * 4; i += 256) {
            const int px_g = i >> 2, c = i & 3;
            int tile = 0, px = px_g;
            if (IPB == 4) { tile = px_g / APX; px = px_g - tile * APX; }
            const int gy = regY0 - 1 + px / ATX;
            const int gx = regX0 - 1 + px % ATX;
            const int bimg = (IPB == 1) ? img : ((int)blockIdx.x * 4 + tile);
            uint4 v = {0u, 0u, 0u, 0u};
            if ((unsigned)gy < (unsigned)H && (unsigned)gx < (unsigned)W)
                v = *(const uint4*)&in[((bimg * H + gy) * W + gx) * CI + cib + c * 16];
            *(uint4*)&lds[c * APLANE + px_g * 16] = v;
        }
        for (int i = tid; i < 2304; i += 256) {
            const int row = i >> 2, c = i & 3;
            const int co_l = row / 9, tap = row - co_l * 9;
            uint4 v = *(const uint4*)&wt[((co_base + co_l) * 9 + tap) * CI + cib + c * 16];
            *(uint4*)&lds[WBASE + c * WPLANE + row * 16] = v;
        }
        __syncthreads();

#pragma unroll
        for (int tap = 0; tap < 9; ++tap) {
            const int toff = ((tap / 3) * ATX + (tap % 3)) * 16;
            v4i bf[4], af[4];
#pragma unroll
            for (int cs = 0; cs < 4; ++cs)
                bf[cs] = *(const v4i*)&lds[wbase[cs] + tap * 16];
#pragma unroll
            for (int ps = 0; ps < 4; ++ps)
                af[ps] = *(const v4i*)&lds[abase[ps] + toff];
#pragma unroll
            for (int ps = 0; ps < 4; ++ps)
#pragma unroll
                for (int cs = 0; cs < 4; ++cs)
                    acc[ps][cs] = __builtin_amdgcn_mfma_i32_16x16x64_i8(
                        af[ps], bf[cs], acc[ps][cs], 0, 0, 0);
        }
    }

    const int bimg = (IPB == 1) ? img : ((int)blockIdx.x * 4 + w);
#pragma unroll
    for (int cs = 0; cs < 4; ++cs) {
        const int co = co_base + cs * 16 + n;
        const double gg = (double)gvec[co];
        const double bb = (double)bvec[co];
#pragma unroll
        for (int ps = 0; ps < 4; ++ps) {
            const int Yb = regY0 + wy8 + (ps >> 1) * 4 + (q >> 1) * 2;
            const int Xb = regX0 + wx8 + (ps & 1) * 4 + (q & 1) * 2;
            int r4[4];
#pragma unroll
            for (int r = 0; r < 4; ++r) {
                double conv = (double)acc[ps][cs][r] / 49.0;
                double y = conv * gg + bb;
                double t = fmin(fmax(y, -1.0), 1.0) * 7.0;
                int qi = (int)rint(t);
                r4[r] = qi > 0 ? qi : 0;
            }
            if (POOL) {
                int m = max(max(r4[0], r4[1]), max(r4[2], r4[3]));
                out[((bimg * (H / 2) + (Yb >> 1)) * (W / 2) + (Xb >> 1)) * CO + co] = (unsigned char)m;
            } else {
#pragma unroll
                for (int r = 0; r < 4; ++r) {
                    const int Y = Yb + (r >> 1), X = Xb + (r & 1);
                    out[((bimg * H + Y) * W + X) * CO + co] = (unsigned char)r4[r];
                }
            }
        }
    }
}

// ---------------------------------------------------------------------------
// FC1: h[512][4096] u8 x wt[512][4096] i8 -> u8 [512][512]
// ---------------------------------------------------------------------------
__global__ __launch_bounds__(256, 2) void fc1_i8_k(
    const unsigned char* __restrict__ h, const signed char* __restrict__ wt,
    const float* __restrict__ gvec, const float* __restrict__ bvec,
    unsigned char* __restrict__ out)
{
    __shared__ int red[4096];
    const int tid = threadIdx.x;
    const int l = tid & 63, w = tid >> 6;
    const int n = l & 15, q = l >> 4;
    const int m0 = blockIdx.x * 32, n0 = blockIdx.y * 32;

    v4i acc[2][2];
#pragma unroll
    for (int a = 0; a < 2; ++a)
#pragma unroll
        for (int b = 0; b < 2; ++b) acc[a][b] = (v4i)0;

    const int kb = w * 1024;
    for (int ks = 0; ks < 16; ++ks) {
        const int k = kb + ks * 64 + q * 16;
        v4i af[2], bf[2];
#pragma unroll
        for (int ms = 0; ms < 2; ++ms)
            af[ms] = *(const v4i*)&h[(m0 + ms * 16 + n) * 4096 + k];
#pragma unroll
        for (int ns = 0; ns < 2; ++ns)
            bf[ns] = *(const v4i*)&wt[(n0 + ns * 16 + n) * 4096 + k];
#pragma unroll
        for (int ms = 0; ms < 2; ++ms)
#pragma unroll
            for (int ns = 0; ns < 2; ++ns)
                acc[ms][ns] = __builtin_amdgcn_mfma_i32_16x16x64_i8(
                    af[ms], bf[ns], acc[ms][ns], 0, 0, 0);
    }

#pragma unroll
    for (int ms = 0; ms < 2; ++ms)
#pragma unroll
        for (int ns = 0; ns < 2; ++ns)
#pragma unroll
            for (int r = 0; r < 4; ++r)
                red[w * 1024 + (ms * 16 + q * 4 + r) * 32 + ns * 16 + n] = acc[ms][ns][r];
    __syncthreads();

#pragma unroll
    for (int j = 0; j < 4; ++j) {
        const int e = tid * 4 + j;
        int s = red[e] + red[1024 + e] + red[2048 + e] + red[3072 + e];
        const int ml = e >> 5, nl = e & 31;
        const int co = n0 + nl;
        double y = ((double)s / 49.0) * (double)gvec[co] + (double)bvec[co];
        double t = fmin(fmax(y, -1.0), 1.0) * 7.0;
        int qi = (int)rint(t);
        qi = qi > 0 ? qi : 0;
        out[(m0 + ml) * 512 + co] = (unsigned char)qi;
    }
}

// FC2
__global__ __launch_bounds__(256) void fc2_k(
    const unsigned char* __restrict__ h, const signed char* __restrict__ wq,
    const float* __restrict__ gvec, const float* __restrict__ bvec,
    float* __restrict__ out)
{
    const int gid = blockIdx.x * 256 + threadIdx.x;
    const int b = gid >> 4;
    const int n = gid & 15;
    if (b >= 512 || n >= 10) return;
    int s = 0;
    for (int k = 0; k < 512; ++k)
        s += (int)h[b * 512 + k] * (int)wq[n * 512 + k];
    double y = ((double)s / 49.0) * (double)gvec[n] + (double)bvec[n];
    double t = fmin(fmax(y, -1.0), 1.0) * 7.0;
    double r = rint(t);
    out[b * 10 + n] = (float)(r / 7.0);
}

// ---------------------------------------------------------------------------
extern "C" void kernel_launch(void* const* d_in, const int* in_sizes, int n_in,
                              void* d_out, int out_size, void* d_ws, size_t ws_size,
                              hipStream_t stream) {
    const float* x   = (const float*)d_in[0];
    const float* w1  = (const float*)d_in[1];
    const float* g1  = (const float*)d_in[2];
    const float* b1  = (const float*)d_in[3];
    const float* w2  = (const float*)d_in[4];
    const float* g2  = (const float*)d_in[5];
    const float* b2  = (const float*)d_in[6];
    const float* w3  = (const float*)d_in[7];
    const float* g3  = (const float*)d_in[8];
    const float* b3  = (const float*)d_in[9];
    const float* w4  = (const float*)d_in[10];
    const float* g4  = (const float*)d_in[11];
    const float* b4  = (const float*)d_in[12];
    const float* w5  = (const float*)d_in[13];
    const float* g5  = (const float*)d_in[14];
    const float* b5  = (const float*)d_in[15];
    const float* w6  = (const float*)d_in[16];
    const float* g6  = (const float*)d_in[17];
    const float* b6  = (const float*)d_in[18];
    const float* wf1 = (const float*)d_in[19];
    const float* gf1 = (const float*)d_in[20];
    const float* bf1 = (const float*)d_in[21];
    const float* wf2 = (const float*)d_in[22];
    const float* gf2 = (const float*)d_in[23];
    const float* bf2 = (const float*)d_in[24];

    char* ws = (char*)d_ws;
    double*        wd1  = (double*)(ws + O_WD1);
    float*         ws1  = (float*)(ws + O_WS1);
    signed char*   qwf2 = (signed char*)(ws + O_QWF2);
    signed char*   qwt2 = (signed char*)(ws + O_QWT2);
    signed char*   qwt3 = (signed char*)(ws + O_QWT3);
    signed char*   qwt4 = (signed char*)(ws + O_QWT4);
    signed char*   qwt5 = (signed char*)(ws + O_QWT5);
    signed char*   qwt6 = (signed char*)(ws + O_QWT6);
    signed char*   qwf1 = (signed char*)(ws + O_QWF1);
    unsigned char* bufA = (unsigned char*)(ws + O_BUFA);
    unsigned char* bufB = (unsigned char*)(ws + O_BUFB);
    unsigned*      cnt  = (unsigned*)(ws + O_CNT);
    unsigned*      list = (unsigned*)(ws + O_LIST);

    // fused weight prep (zeroes fixup counter)
    hipLaunchKernelGGL(prep_k, dim3((S_END + 255) / 256), dim3(256), 0, stream,
                       w1, w2, w3, w4, w5, w6, wf1, wf2, ws);

    // conv1 (fp32 + screening) then exact fixup of flagged outputs
    hipLaunchKernelGGL(conv1_k, dim3(2048, 4), dim3(256), 0, stream,
                       x, ws1, g1, b1, bufA, cnt, list);
    hipLaunchKernelGGL(fixup1_k, dim3(256), dim3(256), 0, stream,
                       x, wd1, g1, b1, bufA, cnt, list);

    // conv stack (round-4 structure)
    hipLaunchKernelGGL((conv_i8_k<64,  64,  32, 32, true,  1>), dim3(2048, 1), dim3(256), 0, stream, bufA, qwt2, g2, b2, bufB);
    hipLaunchKernelGGL((conv_i8_k<64,  128, 16, 16, false, 1>), dim3(512,  2), dim3(256), 0, stream, bufB, qwt3, g3, b3, bufA);
    hipLaunchKernelGGL((conv_i8_k<128, 128, 16, 16, true,  1>), dim3(512,  2), dim3(256), 0, stream, bufA, qwt4, g4, b4, bufB);
    hipLaunchKernelGGL((conv_i8_k<128, 256, 8,  8,  false, 4>), dim3(128,  4), dim3(256), 0, stream, bufB, qwt5, g5, b5, bufA);
    hipLaunchKernelGGL((conv_i8_k<256, 256, 8,  8,  true,  4>), dim3(128,  4), dim3(256), 0, stream, bufA, qwt6, g6, b6, bufB);

    // FC head
    hipLaunchKernelGGL(fc1_i8_k, dim3(16, 16), dim3(256), 0, stream, bufB, qwf1, gf1, bf1, bufA);
    hipLaunchKernelGGL(fc2_k, dim3(32), dim3(256), 0, stream, bufA, qwf2, gf2, bf2, (float*)d_out);
}

// Round 8
// 473.584 us; speedup vs baseline: 1.5022x; 1.5022x over previous
//
#include <hip/hip_runtime.h>

// ---------------------------------------------------------------------------
// IntegerCifar10Net: 4-bit quantized CNN, B=512.
// Post-layer-1 math is EXACT integer arithmetic (acts 0..7, weights -7..7)
// on i8 MFMA (mfma_i32_16x16x64_i8). conv1 = round-5 exact-fp64 kernel
// (76us measured; fp64 quarter-rate issue floor ~50us -- accepted).
// conv2-4: NEW 512px-block kernel: wave tile 128px x 64co (8x4 fragments,
// 12 ds_read_b128 per 32 MFMA vs r4's 8 per 16 -> MFMA-bound), weights
// staged per tap-row group (3 taps, double-buffered 2x12.5KB) to fit 64KB.
// conv3/4 store interior-only act tiles (halo = zero pad ring -> cndmask
// redirect to LDS zero block) with XOR bank swizzle.
// conv5/6 + FC: round-4 kernels (best measured). Epilogue fp64 affine+rint.
// ---------------------------------------------------------------------------

typedef __attribute__((ext_vector_type(4))) int v4i;

// workspace offsets (bytes)
#define O_WD1    0u          // 13824   f64 conv1 [64][3][9]
#define O_WS1    13824u      // 6912    f32 (unused this round, kept in prep)
#define O_QWF2   20736u      // 5120    i8 fc2 [10][512]
#define O_QWT2   25856u      // 36864   i8 [64][9][64]
#define O_QWT3   62720u      // 73728   i8 [128][9][64]
#define O_QWT4   136448u     // 147456  i8 [128][9][128]
#define O_QWT5   283904u     // 294912  i8 [256][9][128]
#define O_QWT6   578816u     // 589824  i8 [256][9][256]
#define O_QWF1   1168640u    // 2097152 i8 [512][4096] nhwc-k
#define O_BUFA   3265792u    // 33.5 MB
#define O_BUFB   36820224u   // 8.4 MB

// prep segment boundaries (element index)
#define S_W1   0
#define S_WF2  1728
#define S_W2   6848
#define S_W3   43712
#define S_W4   117440
#define S_W5   264896
#define S_W6   559808
#define S_WF1  1149632
#define S_END  3246784

// ---------------------------------------------------------------------------
// fused weight prep
// ---------------------------------------------------------------------------
__device__ __forceinline__ int qround(float w) {
    double t = fmin(fmax((double)w, -1.0), 1.0) * 7.0;
    return (int)rint(t);
}

__global__ void prep_k(const float* __restrict__ w1, const float* __restrict__ w2,
                       const float* __restrict__ w3, const float* __restrict__ w4,
                       const float* __restrict__ w5, const float* __restrict__ w6,
                       const float* __restrict__ wf1, const float* __restrict__ wf2,
                       char* __restrict__ ws) {
    int i = blockIdx.x * 256 + threadIdx.x;
    if (i >= S_END) return;
    if (i < S_WF2) {
        int r = qround(w1[i]);
        ((double*)(ws + O_WD1))[i] = (double)r;
        ((float*)(ws + O_WS1))[i]  = (float)r;
    } else if (i < S_W2) {
        int j = i - S_WF2;
        ((signed char*)(ws + O_QWF2))[j] = (signed char)qround(wf2[j]);
    } else if (i < S_WF1) {
        const float* src; signed char* dst; int CI, j;
        if      (i < S_W3) { src = w2; dst = (signed char*)(ws + O_QWT2); CI = 64;  j = i - S_W2; }
        else if (i < S_W4) { src = w3; dst = (signed char*)(ws + O_QWT3); CI = 64;  j = i - S_W3; }
        else if (i < S_W5) { src = w4; dst = (signed char*)(ws + O_QWT4); CI = 128; j = i - S_W4; }
        else if (i < S_W6) { src = w5; dst = (signed char*)(ws + O_QWT5); CI = 128; j = i - S_W5; }
        else               { src = w6; dst = (signed char*)(ws + O_QWT6); CI = 256; j = i - S_W6; }
        int co  = j / (9 * CI);
        int rem = j - co * 9 * CI;
        int t   = rem / CI;
        int ci  = rem - t * CI;
        dst[j] = (signed char)qround(src[(co * CI + ci) * 9 + t]);
    } else {
        int j  = i - S_WF1;
        int row = j >> 12;
        int kn  = j & 4095;
        int px  = kn >> 8;
        int c   = kn & 255;
        ((signed char*)(ws + O_QWF1))[j] = (signed char)qround(wf1[row * 4096 + c * 16 + px]);
    }
}

// ---------------------------------------------------------------------------
// conv1: round-5 kernel verbatim (fp64-exact, scalar weight loads, 76us).
// ---------------------------------------------------------------------------
__global__ __launch_bounds__(256) void conv1_k(
    const float* __restrict__ x, const double* __restrict__ wd,
    const float* __restrict__ gvec, const float* __restrict__ bvec,
    unsigned char* __restrict__ out)
{
    __shared__ double xs[3][10][35];

    const int tid  = threadIdx.x;
    const int sp   = tid & 63;
    const int cg   = __builtin_amdgcn_readfirstlane(tid >> 6);
    const int img  = blockIdx.x >> 2;
    const int slab = blockIdx.x & 3;
    const int y0s  = slab * 8;
    const int co_base = blockIdx.y * 16;
    const int co0  = co_base + cg * 4;
    const int yb = sp >> 4, xb = sp & 15;
    const int ysl = yb * 2, x0 = xb * 2;

    for (int i = tid; i < 1020; i += 256) {
        int ci = i / 340, r = i - ci * 340;
        int ry = r / 34, rx = r - ry * 34;
        int gy = y0s - 1 + ry, gx = rx - 1;
        double v = 0.0;
        if ((unsigned)gy < 32u && (unsigned)gx < 32u)
            v = (double)x[(img * 3 + ci) * 1024 + gy * 32 + gx];
        xs[ci][ry][rx] = v;
    }
    __syncthreads();

    double acc[4][4];
#pragma unroll
    for (int l = 0; l < 4; ++l)
#pragma unroll
        for (int p = 0; p < 4; ++p) acc[l][p] = 0.0;

#pragma unroll
    for (int ci = 0; ci < 3; ++ci) {
        double a[4][4];
#pragma unroll
        for (int iy = 0; iy < 4; ++iy)
#pragma unroll
            for (int ix = 0; ix < 4; ++ix)
                a[iy][ix] = xs[ci][ysl + iy][x0 + ix];
#pragma unroll
        for (int l = 0; l < 4; ++l) {
            const double* wp = wd + ((co0 + l) * 3 + ci) * 9;
            double wr[9];
#pragma unroll
            for (int t = 0; t < 9; ++t) wr[t] = wp[t];
#pragma unroll
            for (int ky = 0; ky < 3; ++ky)
#pragma unroll
                for (int kx = 0; kx < 3; ++kx) {
                    const double wv = wr[ky * 3 + kx];
                    acc[l][0] = fma(wv, a[ky    ][kx    ], acc[l][0]);
                    acc[l][1] = fma(wv, a[ky    ][kx + 1], acc[l][1]);
                    acc[l][2] = fma(wv, a[ky + 1][kx    ], acc[l][2]);
                    acc[l][3] = fma(wv, a[ky + 1][kx + 1], acc[l][3]);
                }
        }
    }

#pragma unroll
    for (int l = 0; l < 4; ++l) {
        const int co = co0 + l;
        const double gg = (double)gvec[co];
        const double bb = (double)bvec[co];
#pragma unroll
        for (int p = 0; p < 4; ++p) {
            double conv = acc[l][p] / 7.0;
            double y = conv * gg + bb;
            double t = fmin(fmax(y, -1.0), 1.0) * 7.0;
            int q = (int)rint(t);
            q = q > 0 ? q : 0;
            const int Y = y0s + ysl + (p >> 1), X = x0 + (p & 1);
            out[((img * 32 + Y) * 32 + X) * 64 + co] = (unsigned char)q;
        }
    }
}

// ---------------------------------------------------------------------------
// NEW big-tile i8 conv (conv2-4). Block 512 px x 64 co; wave 128 px x 64 co
// = 8x4 fragments of 16x16x64 -> 12 ds_read_b128 per 32 MFMA.
// Weights staged per tap-row group (3 taps), double-buffered.
// MODE 0: conv2 (32x32, halo tile, half-image per block).
// MODE 1: conv3/4 (16x16, 2 full imgs per block, interior-only acts,
//         zero-halo via cndmask->ZOFF, XOR bank swizzle).
// ---------------------------------------------------------------------------
template<int CI, int CO, bool POOL, int MODE>
__global__ __launch_bounds__(256, 2) void conv_big_k(
    const unsigned char* __restrict__ in, const signed char* __restrict__ wt,
    const float* __restrict__ gvec, const float* __restrict__ bvec,
    unsigned char* __restrict__ out)
{
    constexpr int H = (MODE == 0) ? 32 : 16;
    constexpr int W = H;
    constexpr int NPASS    = CI / 64;
    constexpr int APX      = (MODE == 0) ? (18 * 34) : 512;
    constexpr int APLANE   = (MODE == 0) ? (APX * 16) : (APX * 16 + 64); // +64: bank-stagger planes
    constexpr int WOFF     = 4 * APLANE;
    constexpr int WPLANE_G = 192 * 16 + 64;   // 3136, bank-staggered
    constexpr int WGBUF    = 4 * WPLANE_G;    // 12544
    constexpr int ZOFF     = WOFF + 2 * WGBUF;
    constexpr int LDSZ     = ZOFF + ((MODE == 1) ? 16 : 0);

    __shared__ __align__(16) char lds[LDSZ];

    const int tid = threadIdx.x;
    const int l   = tid & 63;
    const int w   = tid >> 6;
    const int n   = l & 15;
    const int q   = l >> 4;
    const int co_base = blockIdx.y * 64;
    const int ly = ((n >> 3) & 1) * 2 + ((n >> 1) & 1);
    const int lx = ((n >> 2) & 1) * 2 + (n & 1);

    int img = 0, y0s = 0, bimg0 = 0;
    if (MODE == 0) { img = blockIdx.x >> 1; y0s = (blockIdx.x & 1) * 16; }
    else           { bimg0 = blockIdx.x * 2; }

    int abase[8], ayb[8], axb[8];
    if (MODE == 0) {
#pragma unroll
        for (int ps = 0; ps < 8; ++ps) {
            int ay0 = (ps >> 1) * 4 + ly;
            int ax0 = w * 8 + (ps & 1) * 4 + lx;
            abase[ps] = q * APLANE + (ay0 * 34 + ax0) * 16;
            ayb[ps] = 0; axb[ps] = 0;
        }
    } else {
        const int img_l = w >> 1, half = w & 1;
#pragma unroll
        for (int ps = 0; ps < 8; ++ps) {
            ayb[ps] = half * 8 + (ps >> 2) * 4 + ly - 1;
            axb[ps] = (ps & 3) * 4 + lx - 1;
            abase[ps] = q * APLANE + img_l * (256 * 16);
        }
    }
    int wbase[4];
#pragma unroll
    for (int cs = 0; cs < 4; ++cs)
        wbase[cs] = WOFF + q * WPLANE_G + ((cs * 16 + n) * 3) * 16;

    auto stage_acts = [&](int pass) {
        const int cib = pass * 64;
        if (MODE == 0) {
            for (int i = tid; i < 2448; i += 256) {
                int px_g = i >> 2, c = i & 3;
                int ry = px_g / 34, rx = px_g - ry * 34;
                int gy = y0s - 1 + ry, gx = rx - 1;
                uint4 v = {0u, 0u, 0u, 0u};
                if ((unsigned)gy < 32u && (unsigned)gx < 32u)
                    v = *(const uint4*)&in[((img * 32 + gy) * 32 + gx) * CI + cib + c * 16];
                *(uint4*)&lds[c * APLANE + px_g * 16] = v;
            }
        } else {
            for (int i = tid; i < 2048; i += 256) {
                int px_g = i >> 2, c = i & 3;
                int il = px_g >> 8, pr = px_g & 255;
                int py = pr >> 4, pxx = pr & 15;
                int sx = pxx ^ ((py & 1) << 2);
                uint4 v = *(const uint4*)&in[(((bimg0 + il) * 16 + py) * 16 + pxx) * CI + cib + c * 16];
                *(uint4*)&lds[c * APLANE + (il * 256 + py * 16 + sx) * 16] = v;
            }
            if (tid == 0) { uint4 z = {0u,0u,0u,0u}; *(uint4*)&lds[ZOFF] = z; }
        }
    };
    auto load_wg = [&](int pass, int g, uint4* wpre) {
        const int cib = pass * 64;
#pragma unroll
        for (int k = 0; k < 3; ++k) {
            int i = tid + k * 256;
            int row = i >> 2, c = i & 3;
            int co_l = row / 3, tl = row - co_l * 3;
            wpre[k] = *(const uint4*)&wt[((co_base + co_l) * 9 + g * 3 + tl) * CI + cib + c * 16];
        }
    };
    auto write_wg = [&](int buf, const uint4* wpre) {
#pragma unroll
        for (int k = 0; k < 3; ++k) {
            int i = tid + k * 256;
            int row = i >> 2, c = i & 3;
            *(uint4*)&lds[WOFF + buf * WGBUF + c * WPLANE_G + row * 16] = wpre[k];
        }
    };

    v4i acc[8][4];
#pragma unroll
    for (int ps = 0; ps < 8; ++ps)
#pragma unroll
        for (int cs = 0; cs < 4; ++cs) acc[ps][cs] = (v4i)0;

    auto computeg = [&](int g, int buf) {
#pragma unroll
        for (int tl = 0; tl < 3; ++tl) {
            v4i bf[4];
#pragma unroll
            for (int cs = 0; cs < 4; ++cs)
                bf[cs] = *(const v4i*)&lds[wbase[cs] + buf * WGBUF + tl * 16];
#pragma unroll
            for (int h = 0; h < 2; ++h) {
                v4i af[4];
#pragma unroll
                for (int pp = 0; pp < 4; ++pp) {
                    const int ps = h * 4 + pp;
                    int addr;
                    if (MODE == 0) {
                        addr = abase[ps] + (g * 34 + tl) * 16;
                    } else {
                        int py  = ayb[ps] + g;
                        int pxx = axb[ps] + tl;
                        bool ok = ((unsigned)py < 16u) && ((unsigned)pxx < 16u);
                        int sx  = pxx ^ ((py & 1) << 2);
                        int a2  = abase[ps] + (py * 16 + sx) * 16;
                        addr = ok ? a2 : ZOFF;
                    }
                    af[pp] = *(const v4i*)&lds[addr];
                }
#pragma unroll
                for (int pp = 0; pp < 4; ++pp)
#pragma unroll
                    for (int cs = 0; cs < 4; ++cs)
                        acc[h * 4 + pp][cs] = __builtin_amdgcn_mfma_i32_16x16x64_i8(
                            af[pp], bf[cs], acc[h * 4 + pp][cs], 0, 0, 0);
            }
        }
    };

    uint4 wpre[3];
    stage_acts(0);
    load_wg(0, 0, wpre);
    write_wg(0, wpre);
    __syncthreads();
    for (int pass = 0;;) {
#pragma unroll
        for (int g = 0; g < 3; ++g) {
            if (g < 2) load_wg(pass, g + 1, wpre);
            computeg(g, g & 1);
            if (g < 2) { write_wg((g + 1) & 1, wpre); __syncthreads(); }
        }
        if (++pass == NPASS) break;
        __syncthreads();          // protect acts/buf0 WAR from g=2 compute
        stage_acts(pass);
        load_wg(pass, 0, wpre);
        write_wg(0, wpre);
        __syncthreads();
    }

    // epilogue: fp64 affine+quant+relu (+intra-lane 2x2 pool)
    const int bimg = (MODE == 0) ? img : (bimg0 + (w >> 1));
#pragma unroll
    for (int cs = 0; cs < 4; ++cs) {
        const int co = co_base + cs * 16 + n;
        const double gg = (double)gvec[co];
        const double bb = (double)bvec[co];
#pragma unroll
        for (int ps = 0; ps < 8; ++ps) {
            int ry, rx;
            if (MODE == 0) { ry = y0s + (ps >> 1) * 4; rx = w * 8 + (ps & 1) * 4; }
            else           { ry = (w & 1) * 8 + (ps >> 2) * 4; rx = (ps & 3) * 4; }
            const int Yb = ry + (q >> 1) * 2;
            const int Xb = rx + (q & 1) * 2;
            int r4[4];
#pragma unroll
            for (int r = 0; r < 4; ++r) {
                double conv = (double)acc[ps][cs][r] / 49.0;
                double y = conv * gg + bb;
                double t = fmin(fmax(y, -1.0), 1.0) * 7.0;
                int qi = (int)rint(t);
                r4[r] = qi > 0 ? qi : 0;
            }
            if (POOL) {
                int m = max(max(r4[0], r4[1]), max(r4[2], r4[3]));
                out[((bimg * (H / 2) + (Yb >> 1)) * (W / 2) + (Xb >> 1)) * CO + co] = (unsigned char)m;
            } else {
#pragma unroll
                for (int r = 0; r < 4; ++r) {
                    const int Y = Yb + (r >> 1), X = Xb + (r & 1);
                    out[((bimg * H + Y) * W + X) * CO + co] = (unsigned char)r4[r];
                }
            }
        }
    }
}

// ---------------------------------------------------------------------------
// round-4 i8 conv (kept for conv5/6)
// ---------------------------------------------------------------------------
template<int CI, int CO, int H, int W, bool POOL, int IPB>
__global__ __launch_bounds__(256, 2) void conv_i8_k(
    const unsigned char* __restrict__ in, const signed char* __restrict__ wt,
    const float* __restrict__ gvec, const float* __restrict__ bvec,
    unsigned char* __restrict__ out)
{
    constexpr int ATX    = (IPB == 1) ? 18 : 10;
    constexpr int APX    = ATX * ATX;
    constexpr int APLANE = IPB * APX * 16;
    constexpr int WBASE  = 4 * APLANE;
    constexpr int WPLANE = 576 * 16;
    constexpr int NPASS  = CI / 64;

    __shared__ __align__(16) char lds[WBASE + 4 * WPLANE];

    const int tid = threadIdx.x;
    const int l   = tid & 63;
    const int w   = tid >> 6;
    const int n   = l & 15;
    const int q   = l >> 4;

    int img = 0, regY0 = 0, regX0 = 0, wy8 = 0, wx8 = 0, tilepx = 0;
    if (IPB == 1) {
        constexpr int rpw = W / 16;
        constexpr int rpi = (H / 16) * rpw;
        img   = blockIdx.x / rpi;
        int r = blockIdx.x % rpi;
        regY0 = (r / rpw) * 16;
        regX0 = (r % rpw) * 16;
        wy8 = (w >> 1) * 8; wx8 = (w & 1) * 8;
    } else {
        tilepx = w * APX;
    }
    const int co_base = blockIdx.y * 64;

    const int ly = ((n >> 3) & 1) * 2 + ((n >> 1) & 1);
    const int lx = ((n >> 2) & 1) * 2 + (n & 1);

    int abase[4], wbase[4];
#pragma unroll
    for (int ps = 0; ps < 4; ++ps) {
        int ay0 = wy8 + (ps >> 1) * 4 + ly;
        int ax0 = wx8 + (ps & 1) * 4 + lx;
        abase[ps] = q * APLANE + (tilepx + ay0 * ATX + ax0) * 16;
    }
#pragma unroll
    for (int cs = 0; cs < 4; ++cs)
        wbase[cs] = WBASE + q * WPLANE + ((cs * 16 + n) * 9) * 16;

    v4i acc[4][4];
#pragma unroll
    for (int ps = 0; ps < 4; ++ps)
#pragma unroll
        for (int cs = 0; cs < 4; ++cs)
            acc[ps][cs] = (v4i)0;

    for (int pass = 0; pass < NPASS; ++pass) {
        const int cib = pass * 64;
        __syncthreads();
        for (int i = tid; i < IPB * APX * 4; i += 256) {
            const int px_g = i >> 2, c = i & 3;
            int tile = 0, px = px_g;
            if (IPB == 4) { tile = px_g / APX; px = px_g - tile * APX; }
            const int gy = regY0 - 1 + px / ATX;
            const int gx = regX0 - 1 + px % ATX;
            const int bimg = (IPB == 1) ? img : ((int)blockIdx.x * 4 + tile);
            uint4 v = {0u, 0u, 0u, 0u};
            if ((unsigned)gy < (unsigned)H && (unsigned)gx < (unsigned)W)
                v = *(const uint4*)&in[((bimg * H + gy) * W + gx) * CI + cib + c * 16];
            *(uint4*)&lds[c * APLANE + px_g * 16] = v;
        }
        for (int i = tid; i < 2304; i += 256) {
            const int row = i >> 2, c = i & 3;
            const int co_l = row / 9, tap = row - co_l * 9;
            uint4 v = *(const uint4*)&wt[((co_base + co_l) * 9 + tap) * CI + cib + c * 16];
            *(uint4*)&lds[WBASE + c * WPLANE + row * 16] = v;
        }
        __syncthreads();

#pragma unroll
        for (int tap = 0; tap < 9; ++tap) {
            const int toff = ((tap / 3) * ATX + (tap % 3)) * 16;
            v4i bf[4], af[4];
#pragma unroll
            for (int cs = 0; cs < 4; ++cs)
                bf[cs] = *(const v4i*)&lds[wbase[cs] + tap * 16];
#pragma unroll
            for (int ps = 0; ps < 4; ++ps)
                af[ps] = *(const v4i*)&lds[abase[ps] + toff];
#pragma unroll
            for (int ps = 0; ps < 4; ++ps)
#pragma unroll
                for (int cs = 0; cs < 4; ++cs)
                    acc[ps][cs] = __builtin_amdgcn_mfma_i32_16x16x64_i8(
                        af[ps], bf[cs], acc[ps][cs], 0, 0, 0);
        }
    }

    const int bimg = (IPB == 1) ? img : ((int)blockIdx.x * 4 + w);
#pragma unroll
    for (int cs = 0; cs < 4; ++cs) {
        const int co = co_base + cs * 16 + n;
        const double gg = (double)gvec[co];
        const double bb = (double)bvec[co];
#pragma unroll
        for (int ps = 0; ps < 4; ++ps) {
            const int Yb = regY0 + wy8 + (ps >> 1) * 4 + (q >> 1) * 2;
            const int Xb = regX0 + wx8 + (ps & 1) * 4 + (q & 1) * 2;
            int r4[4];
#pragma unroll
            for (int r = 0; r < 4; ++r) {
                double conv = (double)acc[ps][cs][r] / 49.0;
                double y = conv * gg + bb;
                double t = fmin(fmax(y, -1.0), 1.0) * 7.0;
                int qi = (int)rint(t);
                r4[r] = qi > 0 ? qi : 0;
            }
            if (POOL) {
                int m = max(max(r4[0], r4[1]), max(r4[2], r4[3]));
                out[((bimg * (H / 2) + (Yb >> 1)) * (W / 2) + (Xb >> 1)) * CO + co] = (unsigned char)m;
            } else {
#pragma unroll
                for (int r = 0; r < 4; ++r) {
                    const int Y = Yb + (r >> 1), X = Xb + (r & 1);
                    out[((bimg * H + Y) * W + X) * CO + co] = (unsigned char)r4[r];
                }
            }
        }
    }
}

// ---------------------------------------------------------------------------
// FC1: h[512][4096] u8 x wt[512][4096] i8 -> u8 [512][512]
// ---------------------------------------------------------------------------
__global__ __launch_bounds__(256, 2) void fc1_i8_k(
    const unsigned char* __restrict__ h, const signed char* __restrict__ wt,
    const float* __restrict__ gvec, const float* __restrict__ bvec,
    unsigned char* __restrict__ out)
{
    __shared__ int red[4096];
    const int tid = threadIdx.x;
    const int l = tid & 63, w = tid >> 6;
    const int n = l & 15, q = l >> 4;
    const int m0 = blockIdx.x * 32, n0 = blockIdx.y * 32;

    v4i acc[2][2];
#pragma unroll
    for (int a = 0; a < 2; ++a)
#pragma unroll
        for (int b = 0; b < 2; ++b) acc[a][b] = (v4i)0;

    const int kb = w * 1024;
    for (int ks = 0; ks < 16; ++ks) {
        const int k = kb + ks * 64 + q * 16;
        v4i af[2], bf[2];
#pragma unroll
        for (int ms = 0; ms < 2; ++ms)
            af[ms] = *(const v4i*)&h[(m0 + ms * 16 + n) * 4096 + k];
#pragma unroll
        for (int ns = 0; ns < 2; ++ns)
            bf[ns] = *(const v4i*)&wt[(n0 + ns * 16 + n) * 4096 + k];
#pragma unroll
        for (int ms = 0; ms < 2; ++ms)
#pragma unroll
            for (int ns = 0; ns < 2; ++ns)
                acc[ms][ns] = __builtin_amdgcn_mfma_i32_16x16x64_i8(
                    af[ms], bf[ns], acc[ms][ns], 0, 0, 0);
    }

#pragma unroll
    for (int ms = 0; ms < 2; ++ms)
#pragma unroll
        for (int ns = 0; ns < 2; ++ns)
#pragma unroll
            for (int r = 0; r < 4; ++r)
                red[w * 1024 + (ms * 16 + q * 4 + r) * 32 + ns * 16 + n] = acc[ms][ns][r];
    __syncthreads();

#pragma unroll
    for (int j = 0; j < 4; ++j) {
        const int e = tid * 4 + j;
        int s = red[e] + red[1024 + e] + red[2048 + e] + red[3072 + e];
        const int ml = e >> 5, nl = e & 31;
        const int co = n0 + nl;
        double y = ((double)s / 49.0) * (double)gvec[co] + (double)bvec[co];
        double t = fmin(fmax(y, -1.0), 1.0) * 7.0;
        int qi = (int)rint(t);
        qi = qi > 0 ? qi : 0;
        out[(m0 + ml) * 512 + co] = (unsigned char)qi;
    }
}

// FC2
__global__ __launch_bounds__(256) void fc2_k(
    const unsigned char* __restrict__ h, const signed char* __restrict__ wq,
    const float* __restrict__ gvec, const float* __restrict__ bvec,
    float* __restrict__ out)
{
    const int gid = blockIdx.x * 256 + threadIdx.x;
    const int b = gid >> 4;
    const int n = gid & 15;
    if (b >= 512 || n >= 10) return;
    int s = 0;
    for (int k = 0; k < 512; ++k)
        s += (int)h[b * 512 + k] * (int)wq[n * 512 + k];
    double y = ((double)s / 49.0) * (double)gvec[n] + (double)bvec[n];
    double t = fmin(fmax(y, -1.0), 1.0) * 7.0;
    double r = rint(t);
    out[b * 10 + n] = (float)(r / 7.0);
}

// ---------------------------------------------------------------------------
extern "C" void kernel_launch(void* const* d_in, const int* in_sizes, int n_in,
                              void* d_out, int out_size, void* d_ws, size_t ws_size,
                              hipStream_t stream) {
    const float* x   = (const float*)d_in[0];
    const float* w1  = (const float*)d_in[1];
    const float* g1  = (const float*)d_in[2];
    const float* b1  = (const float*)d_in[3];
    const float* w2  = (const float*)d_in[4];
    const float* g2  = (const float*)d_in[5];
    const float* b2  = (const float*)d_in[6];
    const float* w3  = (const float*)d_in[7];
    const float* g3  = (const float*)d_in[8];
    const float* b3  = (const float*)d_in[9];
    const float* w4  = (const float*)d_in[10];
    const float* g4  = (const float*)d_in[11];
    const float* b4  = (const float*)d_in[12];
    const float* w5  = (const float*)d_in[13];
    const float* g5  = (const float*)d_in[14];
    const float* b5  = (const float*)d_in[15];
    const float* w6  = (const float*)d_in[16];
    const float* g6  = (const float*)d_in[17];
    const float* b6  = (const float*)d_in[18];
    const float* wf1 = (const float*)d_in[19];
    const float* gf1 = (const float*)d_in[20];
    const float* bf1 = (const float*)d_in[21];
    const float* wf2 = (const float*)d_in[22];
    const float* gf2 = (const float*)d_in[23];
    const float* bf2 = (const float*)d_in[24];

    char* ws = (char*)d_ws;
    double*        wd1  = (double*)(ws + O_WD1);
    signed char*   qwf2 = (signed char*)(ws + O_QWF2);
    signed char*   qwt2 = (signed char*)(ws + O_QWT2);
    signed char*   qwt3 = (signed char*)(ws + O_QWT3);
    signed char*   qwt4 = (signed char*)(ws + O_QWT4);
    signed char*   qwt5 = (signed char*)(ws + O_QWT5);
    signed char*   qwt6 = (signed char*)(ws + O_QWT6);
    signed char*   qwf1 = (signed char*)(ws + O_QWF1);
    unsigned char* bufA = (unsigned char*)(ws + O_BUFA);
    unsigned char* bufB = (unsigned char*)(ws + O_BUFB);

    // fused weight prep
    hipLaunchKernelGGL(prep_k, dim3((S_END + 255) / 256), dim3(256), 0, stream,
                       w1, w2, w3, w4, w5, w6, wf1, wf2, ws);

    // conv stack
    hipLaunchKernelGGL(conv1_k, dim3(2048, 4), dim3(256), 0, stream, x, wd1, g1, b1, bufA);
    hipLaunchKernelGGL((conv_big_k<64,  64,  true,  0>), dim3(1024, 1), dim3(256), 0, stream, bufA, qwt2, g2, b2, bufB);
    hipLaunchKernelGGL((conv_big_k<64,  128, false, 1>), dim3(256,  2), dim3(256), 0, stream, bufB, qwt3, g3, b3, bufA);
    hipLaunchKernelGGL((conv_big_k<128, 128, true,  1>), dim3(256,  2), dim3(256), 0, stream, bufA, qwt4, g4, b4, bufB);
    hipLaunchKernelGGL((conv_i8_k<128, 256, 8, 8, false, 4>), dim3(128, 4), dim3(256), 0, stream, bufB, qwt5, g5, b5, bufA);
    hipLaunchKernelGGL((conv_i8_k<256, 256, 8, 8, true,  4>), dim3(128, 4), dim3(256), 0, stream, bufA, qwt6, g6, b6, bufB);

    // FC head
    hipLaunchKernelGGL(fc1_i8_k, dim3(16, 16), dim3(256), 0, stream, bufB, qwf1, gf1, bf1, bufA);
    hipLaunchKernelGGL(fc2_k, dim3(32), dim3(256), 0, stream, bufA, qwf2, gf2, bf2, (float*)d_out);
}

// Round 9
// 445.443 us; speedup vs baseline: 1.5971x; 1.0632x over previous
//
#include <hip/hip_runtime.h>

// ---------------------------------------------------------------------------
// IntegerCifar10Net: 4-bit quantized CNN, B=512.
// Post-layer-1 math is EXACT integer arithmetic (acts 0..7, weights -7..7)
// on i8 MFMA (mfma_i32_16x16x64_i8) -- round-4 conv structure (best measured).
// conv1: fp32 main path + rigorous boundary screen; flagged outputs carry
// bit7 in the output byte; fixup_scan_k re-reads the output, recomputes
// flagged bytes with the PROVEN bit-exact fp64 chain (r2/r5/r7) and clears
// the flag. No atomics, no inline fp64 -- the two measured failure modes.
// Activations NHWC u8 (value = 7 * real). Epilogue fp64 affine+rint.
// ---------------------------------------------------------------------------

typedef __attribute__((ext_vector_type(4))) int v4i;

// workspace offsets (bytes)
#define O_WD1    0u          // 13824   f64 conv1 [64][3][9]
#define O_WS1    13824u      // 6912    f32 conv1 [64][3][9]
#define O_QWF2   20736u      // 5120    i8 fc2 [10][512]
#define O_QWT2   25856u      // 36864   i8 [64][9][64]
#define O_QWT3   62720u      // 73728   i8 [128][9][64]
#define O_QWT4   136448u     // 147456  i8 [128][9][128]
#define O_QWT5   283904u     // 294912  i8 [256][9][128]
#define O_QWT6   578816u     // 589824  i8 [256][9][256]
#define O_QWF1   1168640u    // 2097152 i8 [512][4096] nhwc-k
#define O_BUFA   3265792u    // 33.5 MB
#define O_BUFB   36820224u   // 8.4 MB

// prep segment boundaries (element index)
#define S_W1   0
#define S_WF2  1728
#define S_W2   6848
#define S_W3   43712
#define S_W4   117440
#define S_W5   264896
#define S_W6   559808
#define S_WF1  1149632
#define S_END  3246784

// ---------------------------------------------------------------------------
// fused weight prep
// ---------------------------------------------------------------------------
__device__ __forceinline__ int qround(float w) {
    double t = fmin(fmax((double)w, -1.0), 1.0) * 7.0;
    return (int)rint(t);
}

__global__ void prep_k(const float* __restrict__ w1, const float* __restrict__ w2,
                       const float* __restrict__ w3, const float* __restrict__ w4,
                       const float* __restrict__ w5, const float* __restrict__ w6,
                       const float* __restrict__ wf1, const float* __restrict__ wf2,
                       char* __restrict__ ws) {
    int i = blockIdx.x * 256 + threadIdx.x;
    if (i >= S_END) return;
    if (i < S_WF2) {
        int r = qround(w1[i]);
        ((double*)(ws + O_WD1))[i] = (double)r;
        ((float*)(ws + O_WS1))[i]  = (float)r;
    } else if (i < S_W2) {
        int j = i - S_WF2;
        ((signed char*)(ws + O_QWF2))[j] = (signed char)qround(wf2[j]);
    } else if (i < S_WF1) {
        const float* src; signed char* dst; int CI, j;
        if      (i < S_W3) { src = w2; dst = (signed char*)(ws + O_QWT2); CI = 64;  j = i - S_W2; }
        else if (i < S_W4) { src = w3; dst = (signed char*)(ws + O_QWT3); CI = 64;  j = i - S_W3; }
        else if (i < S_W5) { src = w4; dst = (signed char*)(ws + O_QWT4); CI = 128; j = i - S_W4; }
        else if (i < S_W6) { src = w5; dst = (signed char*)(ws + O_QWT5); CI = 128; j = i - S_W5; }
        else               { src = w6; dst = (signed char*)(ws + O_QWT6); CI = 256; j = i - S_W6; }
        int co  = j / (9 * CI);
        int rem = j - co * 9 * CI;
        int t   = rem / CI;
        int ci  = rem - t * CI;
        dst[j] = (signed char)qround(src[(co * CI + ci) * 9 + t]);
    } else {
        int j  = i - S_WF1;
        int row = j >> 12;
        int kn  = j & 4095;
        int px  = kn >> 8;
        int c   = kn & 255;
        ((signed char*)(ws + O_QWF1))[j] = (signed char)qround(wf1[row * 4096 + c * 16 + px]);
    }
}

// ---------------------------------------------------------------------------
// conv1: fp32 main path, flag-in-bit7 for boundary cases (no atomics, no
// inline fp64). Structure = proven r5 kernel with fp32 types.
// ---------------------------------------------------------------------------
__global__ __launch_bounds__(256) void conv1_k(
    const float* __restrict__ x, const float* __restrict__ wf32,
    const float* __restrict__ gvec, const float* __restrict__ bvec,
    unsigned char* __restrict__ out)
{
    __shared__ float xs[3][10][35];

    const int tid  = threadIdx.x;
    const int sp   = tid & 63;
    const int cg   = __builtin_amdgcn_readfirstlane(tid >> 6);
    const int img  = blockIdx.x >> 2;
    const int slab = blockIdx.x & 3;
    const int y0s  = slab * 8;
    const int co_base = blockIdx.y * 16;
    const int co0  = co_base + cg * 4;        // uniform
    const int yb = sp >> 4, xb = sp & 15;
    const int ysl = yb * 2, x0 = xb * 2;

    for (int i = tid; i < 1020; i += 256) {
        int ci = i / 340, r = i - ci * 340;
        int ry = r / 34, rx = r - ry * 34;
        int gy = y0s - 1 + ry, gx = rx - 1;
        float v = 0.f;
        if ((unsigned)gy < 32u && (unsigned)gx < 32u)
            v = x[(img * 3 + ci) * 1024 + gy * 32 + gx];
        xs[ci][ry][rx] = v;
    }
    __syncthreads();

    float acc[4][4];
    float xa[4];
#pragma unroll
    for (int l = 0; l < 4; ++l)
#pragma unroll
        for (int p = 0; p < 4; ++p) acc[l][p] = 0.f;
#pragma unroll
    for (int p = 0; p < 4; ++p) xa[p] = 0.f;

#pragma unroll
    for (int ci = 0; ci < 3; ++ci) {
        float a[4][4];
#pragma unroll
        for (int iy = 0; iy < 4; ++iy)
#pragma unroll
            for (int ix = 0; ix < 4; ++ix)
                a[iy][ix] = xs[ci][ysl + iy][x0 + ix];
#pragma unroll
        for (int ky = 0; ky < 3; ++ky)
#pragma unroll
            for (int kx = 0; kx < 3; ++kx) {
                xa[0] += fabsf(a[ky    ][kx    ]);
                xa[1] += fabsf(a[ky    ][kx + 1]);
                xa[2] += fabsf(a[ky + 1][kx    ]);
                xa[3] += fabsf(a[ky + 1][kx + 1]);
            }
#pragma unroll
        for (int l = 0; l < 4; ++l) {
            const float* wp = wf32 + ((co0 + l) * 3 + ci) * 9;  // uniform -> s_load
            float wr[9];
#pragma unroll
            for (int t = 0; t < 9; ++t) wr[t] = wp[t];
#pragma unroll
            for (int ky = 0; ky < 3; ++ky)
#pragma unroll
                for (int kx = 0; kx < 3; ++kx) {
                    const float wv = wr[ky * 3 + kx];
                    acc[l][0] = fmaf(wv, a[ky    ][kx    ], acc[l][0]);
                    acc[l][1] = fmaf(wv, a[ky    ][kx + 1], acc[l][1]);
                    acc[l][2] = fmaf(wv, a[ky + 1][kx    ], acc[l][2]);
                    acc[l][3] = fmaf(wv, a[ky + 1][kx + 1], acc[l][3]);
                }
        }
    }

#pragma unroll
    for (int l = 0; l < 4; ++l) {
        const int co = co0 + l;
        const float gg = gvec[co];
        const float bb = bvec[co];
#pragma unroll
        for (int p = 0; p < 4; ++p) {
            float conv = acc[l][p] * (1.f / 7.f);
            float y  = fmaf(conv, gg, bb);
            float t  = fminf(fmaxf(y, -1.f), 1.f) * 7.f;
            // conservative screen (proven bit-exact in r6/r7 runs)
            float tau = fabsf(gg) * xa[p] * 2e-5f + 1e-4f;
            float u = t - floorf(t);
            float d = fabsf(u - 0.5f);
            int q = (int)rintf(t);
            q = q > 0 ? q : 0;
            unsigned char byte = (unsigned char)q;
            if (d <= tau) byte |= 0x80u;        // defer exact recompute
            const int Y = y0s + ysl + (p >> 1), X = x0 + (p & 1);
            out[((img * 32 + Y) * 32 + X) * 64 + co] = byte;
        }
    }
}

// ---------------------------------------------------------------------------
// fixup scan: read conv1 output as uint4; for rare flagged bytes (bit7),
// recompute with the PROVEN bit-exact fp64 chain and clear the flag.
// ---------------------------------------------------------------------------
__global__ __launch_bounds__(256) void fixup_scan_k(
    const float* __restrict__ x, const double* __restrict__ wd64,
    const float* __restrict__ gvec, const float* __restrict__ bvec,
    unsigned char* __restrict__ out)
{
    const int nvec = 33554432 / 16;   // 2,097,152 uint4
    for (int i = blockIdx.x * 256 + threadIdx.x; i < nvec; i += gridDim.x * 256) {
        uint4 v = *(const uint4*)&out[i * 16];
        if (((v.x | v.y | v.z | v.w) & 0x80808080u) == 0u) continue;
#pragma unroll
        for (int b = 0; b < 16; ++b) {
            if (!(out[i * 16 + b] & 0x80u)) continue;
            const unsigned id = (unsigned)(i * 16 + b);
            const int co  = id & 63;
            unsigned r    = id >> 6;
            const int X   = r & 31; r >>= 5;
            const int Y   = r & 31;
            const int img = r >> 5;
            double acc = 0.0;
#pragma unroll
            for (int ci = 0; ci < 3; ++ci)
#pragma unroll
                for (int ky = 0; ky < 3; ++ky)
#pragma unroll
                    for (int kx = 0; kx < 3; ++kx) {
                        const int gy = Y - 1 + ky, gx = X - 1 + kx;
                        double vv = 0.0;
                        if ((unsigned)gy < 32u && (unsigned)gx < 32u)
                            vv = (double)x[(img * 3 + ci) * 1024 + gy * 32 + gx];
                        acc = fma(wd64[(co * 3 + ci) * 9 + ky * 3 + kx], vv, acc);
                    }
            double conv = acc / 7.0;
            double y = conv * (double)gvec[co] + (double)bvec[co];
            double t = fmin(fmax(y, -1.0), 1.0) * 7.0;
            int q = (int)rint(t);
            q = q > 0 ? q : 0;
            out[id] = (unsigned char)q;          // flag cleared
        }
    }
}

// ---------------------------------------------------------------------------
// round-4 i8 MFMA implicit-GEMM conv (best measured) -- conv2..conv6.
// ---------------------------------------------------------------------------
template<int CI, int CO, int H, int W, bool POOL, int IPB>
__global__ __launch_bounds__(256, 2) void conv_i8_k(
    const unsigned char* __restrict__ in, const signed char* __restrict__ wt,
    const float* __restrict__ gvec, const float* __restrict__ bvec,
    unsigned char* __restrict__ out)
{
    constexpr int ATX    = (IPB == 1) ? 18 : 10;
    constexpr int APX    = ATX * ATX;
    constexpr int APLANE = IPB * APX * 16;
    constexpr int WBASE  = 4 * APLANE;
    constexpr int WPLANE = 576 * 16;
    constexpr int NPASS  = CI / 64;

    __shared__ __align__(16) char lds[WBASE + 4 * WPLANE];

    const int tid = threadIdx.x;
    const int l   = tid & 63;
    const int w   = tid >> 6;
    const int n   = l & 15;
    const int q   = l >> 4;

    int img = 0, regY0 = 0, regX0 = 0, wy8 = 0, wx8 = 0, tilepx = 0;
    if (IPB == 1) {
        constexpr int rpw = W / 16;
        constexpr int rpi = (H / 16) * rpw;
        img   = blockIdx.x / rpi;
        int r = blockIdx.x % rpi;
        regY0 = (r / rpw) * 16;
        regX0 = (r % rpw) * 16;
        wy8 = (w >> 1) * 8; wx8 = (w & 1) * 8;
    } else {
        tilepx = w * APX;
    }
    const int co_base = blockIdx.y * 64;

    const int ly = ((n >> 3) & 1) * 2 + ((n >> 1) & 1);
    const int lx = ((n >> 2) & 1) * 2 + (n & 1);

    int abase[4], wbase[4];
#pragma unroll
    for (int ps = 0; ps < 4; ++ps) {
        int ay0 = wy8 + (ps >> 1) * 4 + ly;
        int ax0 = wx8 + (ps & 1) * 4 + lx;
        abase[ps] = q * APLANE + (tilepx + ay0 * ATX + ax0) * 16;
    }
#pragma unroll
    for (int cs = 0; cs < 4; ++cs)
        wbase[cs] = WBASE + q * WPLANE + ((cs * 16 + n) * 9) * 16;

    v4i acc[4][4];
#pragma unroll
    for (int ps = 0; ps < 4; ++ps)
#pragma unroll
        for (int cs = 0; cs < 4; ++cs)
            acc[ps][cs] = (v4i)0;

    for (int pass = 0; pass < NPASS; ++pass) {
        const int cib = pass * 64;
        __syncthreads();
        for (int i = tid; i < IPB * APX * 4; i += 256) {
            const int px_g = i >> 2, c = i & 3;
            int tile = 0, px = px_g;
            if (IPB == 4) { tile = px_g / APX; px = px_g - tile * APX; }
            const int gy = regY0 - 1 + px / ATX;
            const int gx = regX0 - 1 + px % ATX;
            const int bimg = (IPB == 1) ? img : ((int)blockIdx.x * 4 + tile);
            uint4 v = {0u, 0u, 0u, 0u};
            if ((unsigned)gy < (unsigned)H && (unsigned)gx < (unsigned)W)
                v = *(const uint4*)&in[((bimg * H + gy) * W + gx) * CI + cib + c * 16];
            *(uint4*)&lds[c * APLANE + px_g * 16] = v;
        }
        for (int i = tid; i < 2304; i += 256) {
            const int row = i >> 2, c = i & 3;
            const int co_l = row / 9, tap = row - co_l * 9;
            uint4 v = *(const uint4*)&wt[((co_base + co_l) * 9 + tap) * CI + cib + c * 16];
            *(uint4*)&lds[WBASE + c * WPLANE + row * 16] = v;
        }
        __syncthreads();

#pragma unroll
        for (int tap = 0; tap < 9; ++tap) {
            const int toff = ((tap / 3) * ATX + (tap % 3)) * 16;
            v4i bf[4], af[4];
#pragma unroll
            for (int cs = 0; cs < 4; ++cs)
                bf[cs] = *(const v4i*)&lds[wbase[cs] + tap * 16];
#pragma unroll
            for (int ps = 0; ps < 4; ++ps)
                af[ps] = *(const v4i*)&lds[abase[ps] + toff];
#pragma unroll
            for (int ps = 0; ps < 4; ++ps)
#pragma unroll
                for (int cs = 0; cs < 4; ++cs)
                    acc[ps][cs] = __builtin_amdgcn_mfma_i32_16x16x64_i8(
                        af[ps], bf[cs], acc[ps][cs], 0, 0, 0);
        }
    }

    const int bimg = (IPB == 1) ? img : ((int)blockIdx.x * 4 + w);
#pragma unroll
    for (int cs = 0; cs < 4; ++cs) {
        const int co = co_base + cs * 16 + n;
        const double gg = (double)gvec[co];
        const double bb = (double)bvec[co];
#pragma unroll
        for (int ps = 0; ps < 4; ++ps) {
            const int Yb = regY0 + wy8 + (ps >> 1) * 4 + (q >> 1) * 2;
            const int Xb = regX0 + wx8 + (ps & 1) * 4 + (q & 1) * 2;
            int r4[4];
#pragma unroll
            for (int r = 0; r < 4; ++r) {
                double conv = (double)acc[ps][cs][r] / 49.0;
                double y = conv * gg + bb;
                double t = fmin(fmax(y, -1.0), 1.0) * 7.0;
                int qi = (int)rint(t);
                r4[r] = qi > 0 ? qi : 0;
            }
            if (POOL) {
                int m = max(max(r4[0], r4[1]), max(r4[2], r4[3]));
                out[((bimg * (H / 2) + (Yb >> 1)) * (W / 2) + (Xb >> 1)) * CO + co] = (unsigned char)m;
            } else {
#pragma unroll
                for (int r = 0; r < 4; ++r) {
                    const int Y = Yb + (r >> 1), X = Xb + (r & 1);
                    out[((bimg * H + Y) * W + X) * CO + co] = (unsigned char)r4[r];
                }
            }
        }
    }
}

// ---------------------------------------------------------------------------
// FC1: h[512][4096] u8 x wt[512][4096] i8 -> u8 [512][512]
// ---------------------------------------------------------------------------
__global__ __launch_bounds__(256, 2) void fc1_i8_k(
    const unsigned char* __restrict__ h, const signed char* __restrict__ wt,
    const float* __restrict__ gvec, const float* __restrict__ bvec,
    unsigned char* __restrict__ out)
{
    __shared__ int red[4096];
    const int tid = threadIdx.x;
    const int l = tid & 63, w = tid >> 6;
    const int n = l & 15, q = l >> 4;
    const int m0 = blockIdx.x * 32, n0 = blockIdx.y * 32;

    v4i acc[2][2];
#pragma unroll
    for (int a = 0; a < 2; ++a)
#pragma unroll
        for (int b = 0; b < 2; ++b) acc[a][b] = (v4i)0;

    const int kb = w * 1024;
    for (int ks = 0; ks < 16; ++ks) {
        const int k = kb + ks * 64 + q * 16;
        v4i af[2], bf[2];
#pragma unroll
        for (int ms = 0; ms < 2; ++ms)
            af[ms] = *(const v4i*)&h[(m0 + ms * 16 + n) * 4096 + k];
#pragma unroll
        for (int ns = 0; ns < 2; ++ns)
            bf[ns] = *(const v4i*)&wt[(n0 + ns * 16 + n) * 4096 + k];
#pragma unroll
        for (int ms = 0; ms < 2; ++ms)
#pragma unroll
            for (int ns = 0; ns < 2; ++ns)
                acc[ms][ns] = __builtin_amdgcn_mfma_i32_16x16x64_i8(
                    af[ms], bf[ns], acc[ms][ns], 0, 0, 0);
    }

#pragma unroll
    for (int ms = 0; ms < 2; ++ms)
#pragma unroll
        for (int ns = 0; ns < 2; ++ns)
#pragma unroll
            for (int r = 0; r < 4; ++r)
                red[w * 1024 + (ms * 16 + q * 4 + r) * 32 + ns * 16 + n] = acc[ms][ns][r];
    __syncthreads();

#pragma unroll
    for (int j = 0; j < 4; ++j) {
        const int e = tid * 4 + j;
        int s = red[e] + red[1024 + e] + red[2048 + e] + red[3072 + e];
        const int ml = e >> 5, nl = e & 31;
        const int co = n0 + nl;
        double y = ((double)s / 49.0) * (double)gvec[co] + (double)bvec[co];
        double t = fmin(fmax(y, -1.0), 1.0) * 7.0;
        int qi = (int)rint(t);
        qi = qi > 0 ? qi : 0;
        out[(m0 + ml) * 512 + co] = (unsigned char)qi;
    }
}

// FC2
__global__ __launch_bounds__(256) void fc2_k(
    const unsigned char* __restrict__ h, const signed char* __restrict__ wq,
    const float* __restrict__ gvec, const float* __restrict__ bvec,
    float* __restrict__ out)
{
    const int gid = blockIdx.x * 256 + threadIdx.x;
    const int b = gid >> 4;
    const int n = gid & 15;
    if (b >= 512 || n >= 10) return;
    int s = 0;
    for (int k = 0; k < 512; ++k)
        s += (int)h[b * 512 + k] * (int)wq[n * 512 + k];
    double y = ((double)s / 49.0) * (double)gvec[n] + (double)bvec[n];
    double t = fmin(fmax(y, -1.0), 1.0) * 7.0;
    double r = rint(t);
    out[b * 10 + n] = (float)(r / 7.0);
}

// ---------------------------------------------------------------------------
extern "C" void kernel_launch(void* const* d_in, const int* in_sizes, int n_in,
                              void* d_out, int out_size, void* d_ws, size_t ws_size,
                              hipStream_t stream) {
    const float* x   = (const float*)d_in[0];
    const float* w1  = (const float*)d_in[1];
    const float* g1  = (const float*)d_in[2];
    const float* b1  = (const float*)d_in[3];
    const float* w2  = (const float*)d_in[4];
    const float* g2  = (const float*)d_in[5];
    const float* b2  = (const float*)d_in[6];
    const float* w3  = (const float*)d_in[7];
    const float* g3  = (const float*)d_in[8];
    const float* b3  = (const float*)d_in[9];
    const float* w4  = (const float*)d_in[10];
    const float* g4  = (const float*)d_in[11];
    const float* b4  = (const float*)d_in[12];
    const float* w5  = (const float*)d_in[13];
    const float* g5  = (const float*)d_in[14];
    const float* b5  = (const float*)d_in[15];
    const float* w6  = (const float*)d_in[16];
    const float* g6  = (const float*)d_in[17];
    const float* b6  = (const float*)d_in[18];
    const float* wf1 = (const float*)d_in[19];
    const float* gf1 = (const float*)d_in[20];
    const float* bf1 = (const float*)d_in[21];
    const float* wf2 = (const float*)d_in[22];
    const float* gf2 = (const float*)d_in[23];
    const float* bf2 = (const float*)d_in[24];

    char* ws = (char*)d_ws;
    double*        wd1  = (double*)(ws + O_WD1);
    float*         ws1  = (float*)(ws + O_WS1);
    signed char*   qwf2 = (signed char*)(ws + O_QWF2);
    signed char*   qwt2 = (signed char*)(ws + O_QWT2);
    signed char*   qwt3 = (signed char*)(ws + O_QWT3);
    signed char*   qwt4 = (signed char*)(ws + O_QWT4);
    signed char*   qwt5 = (signed char*)(ws + O_QWT5);
    signed char*   qwt6 = (signed char*)(ws + O_QWT6);
    signed char*   qwf1 = (signed char*)(ws + O_QWF1);
    unsigned char* bufA = (unsigned char*)(ws + O_BUFA);
    unsigned char* bufB = (unsigned char*)(ws + O_BUFB);

    // fused weight prep
    hipLaunchKernelGGL(prep_k, dim3((S_END + 255) / 256), dim3(256), 0, stream,
                       w1, w2, w3, w4, w5, w6, wf1, wf2, ws);

    // conv1 (fp32 + bit7 flag) then exact fixup scan
    hipLaunchKernelGGL(conv1_k, dim3(2048, 4), dim3(256), 0, stream,
                       x, ws1, g1, b1, bufA);
    hipLaunchKernelGGL(fixup_scan_k, dim3(1024), dim3(256), 0, stream,
                       x, wd1, g1, b1, bufA);

    // conv stack (round-4 kernels, best measured)
    hipLaunchKernelGGL((conv_i8_k<64,  64,  32, 32, true,  1>), dim3(2048, 1), dim3(256), 0, stream, bufA, qwt2, g2, b2, bufB);
    hipLaunchKernelGGL((conv_i8_k<64,  128, 16, 16, false, 1>), dim3(512,  2), dim3(256), 0, stream, bufB, qwt3, g3, b3, bufA);
    hipLaunchKernelGGL((conv_i8_k<128, 128, 16, 16, true,  1>), dim3(512,  2), dim3(256), 0, stream, bufA, qwt4, g4, b4, bufB);
    hipLaunchKernelGGL((conv_i8_k<128, 256, 8,  8,  false, 4>), dim3(128,  4), dim3(256), 0, stream, bufB, qwt5, g5, b5, bufA);
    hipLaunchKernelGGL((conv_i8_k<256, 256, 8,  8,  true,  4>), dim3(128,  4), dim3(256), 0, stream, bufA, qwt6, g6, b6, bufB);

    // FC head
    hipLaunchKernelGGL(fc1_i8_k, dim3(16, 16), dim3(256), 0, stream, bufB, qwf1, gf1, bf1, bufA);
    hipLaunchKernelGGL(fc2_k, dim3(32), dim3(256), 0, stream, bufA, qwf2, gf2, bf2, (float*)d_out);
}